// Round 1
// baseline (179.745 us; speedup 1.0000x reference)
//
#include <hip/hip_runtime.h>

#define FEAT 256

typedef __attribute__((ext_vector_type(8))) short short8;
typedef __attribute__((ext_vector_type(4))) float floatx4;

__device__ __forceinline__ unsigned short f2bf(float f) {
    unsigned int u = __builtin_bit_cast(unsigned int, f);
    u += 0x7fffu + ((u >> 16) & 1u);   // round-to-nearest-even
    return (unsigned short)(u >> 16);
}

__global__ __launch_bounds__(256, 2) void gdn_kernel(
    const float* __restrict__ x,
    const float* __restrict__ beta,
    const float* __restrict__ gamma,
    float* __restrict__ out,
    int batch)
{
    const int lane = threadIdx.x & 63;
    const int wave = threadIdx.x >> 6;      // 0..3 -> column quarter
    const int l15  = lane & 15;
    const int grp  = lane >> 4;             // 0..3
    const int colbase = wave * 64;

    // ---- One-time: load B fragments (gamma as bf16) into registers.
    // B[nt][ks] element i = gamma[k][col], k = ks*32 + grp*8 + i,
    // col = colbase + nt*16 + l15.  Same k-hat mapping used for A below,
    // so the contraction is correct under any true HW intra-fragment order.
    short8 Bf[4][8];
    #pragma unroll
    for (int nt = 0; nt < 4; ++nt) {
        const int col = colbase + nt * 16 + l15;
        #pragma unroll
        for (int ks = 0; ks < 8; ++ks) {
            const int k0 = ks * 32 + grp * 8;
            short8 b;
            #pragma unroll
            for (int i = 0; i < 8; ++i)
                b[i] = (short)f2bf(gamma[(k0 + i) * FEAT + col]);
            Bf[nt][ks] = b;
        }
    }

    // beta_c per n-tile (col fixed per lane)
    float bc[4];
    #pragma unroll
    for (int nt = 0; nt < 4; ++nt) {
        float bv = beta[colbase + nt * 16 + l15];
        bc[nt] = fmaxf(bv, 1e-6f);
    }

    const int ntiles = batch >> 4;          // 16 rows per tile

    for (int t = blockIdx.x; t < ntiles; t += gridDim.x) {
        const int rb = t << 4;

        // ---- A fragments: x^2 as bf16.  Lane reads row (rb + l15),
        // k = ks*32 + grp*8 + i  (8 consecutive fp32 = 2x dwordx4).
        short8 Af[8];
        const float* xrow = x + (size_t)(rb + l15) * FEAT + grp * 8;
        #pragma unroll
        for (int ks = 0; ks < 8; ++ks) {
            const floatx4* p = (const floatx4*)(xrow + ks * 32);
            floatx4 v0 = p[0];
            floatx4 v1 = p[1];
            short8 a;
            #pragma unroll
            for (int i = 0; i < 4; ++i) {
                a[i]     = (short)f2bf(v0[i] * v0[i]);
                a[4 + i] = (short)f2bf(v1[i] * v1[i]);
            }
            Af[ks] = a;
        }

        // ---- MFMA accumulate over K=256
        floatx4 acc[4] = {{0.f,0.f,0.f,0.f},{0.f,0.f,0.f,0.f},
                          {0.f,0.f,0.f,0.f},{0.f,0.f,0.f,0.f}};
        #pragma unroll
        for (int ks = 0; ks < 8; ++ks) {
            #pragma unroll
            for (int nt = 0; nt < 4; ++nt) {
                acc[nt] = __builtin_amdgcn_mfma_f32_16x16x32_bf16(
                    Af[ks], Bf[nt][ks], acc[nt], 0, 0, 0);
            }
        }

        // ---- Epilogue: y = x * rsqrt(acc + beta_c)
        // C/D layout (verified): col = lane&15, row = (lane>>4)*4 + reg
        #pragma unroll
        for (int nt = 0; nt < 4; ++nt) {
            const int col = colbase + nt * 16 + l15;
            #pragma unroll
            for (int r = 0; r < 4; ++r) {
                const int row = rb + grp * 4 + r;
                const size_t idx = (size_t)row * FEAT + col;
                float np = acc[nt][r] + bc[nt];
                float xv = x[idx];
                out[idx] = xv * rsqrtf(np);
            }
        }
    }
}

extern "C" void kernel_launch(void* const* d_in, const int* in_sizes, int n_in,
                              void* d_out, int out_size, void* d_ws, size_t ws_size,
                              hipStream_t stream) {
    const float* x     = (const float*)d_in[0];
    const float* beta  = (const float*)d_in[1];
    const float* gamma = (const float*)d_in[2];
    float* out = (float*)d_out;

    const int batch = in_sizes[0] / FEAT;   // 262144

    dim3 grid(512);
    dim3 block(256);
    hipLaunchKernelGGL(gdn_kernel, grid, block, 0, stream,
                       x, beta, gamma, out, batch);
}